// Round 19
// baseline (322.815 us; speedup 1.0000x reference)
//
#include <hip/hip_runtime.h>
#include <stdint.h>

#define NUM_CHARS 128
#define BATCH 8192
#define SEQ 40
#define HIDDEN 256
#define ZDIM 1024   /* 4*HIDDEN */
#define SH 264      /* padded h row stride in ushorts */
/* r18 champion (290us) + single-barrier retry under the new low-FETCH regime:
   double-buffered h, ONE __syncthreads/step (one drain instead of two; waves
   may overlap one's gates with another's MFMA tail). r11's failure mode (wave
   drift -> streamed-weight L2 misses, FETCH 59->235MB) is defused: stream is
   now 7 kk and FETCH 10.6MB. LDS: wlds 3 kk (96K) + hbuf[2] (33.8K) + tok (5K)
   + red (1K) = 135.8KB. Partition: kk 0..2 LDS, 3..8 wr (96 regs, AGPR
   overflow), 9..15 streamed (2-slot ring). Cross-step xb prefetch (r13);
   8-wave K-split epilogue + DMA wlds prologue (r15). */

typedef __bf16 bf16x8 __attribute__((ext_vector_type(8)));
typedef float floatx16 __attribute__((ext_vector_type(16)));

__device__ __forceinline__ unsigned short f2bf(float f) {
    union { float f; uint32_t u; } v; v.f = f;
    uint32_t u = v.u;
    u += 0x7FFFu + ((u >> 16) & 1u); // RNE
    return (unsigned short)(u >> 16);
}

// 16B-per-lane DMA: global (per-lane addr) -> LDS (wave-uniform base + lane*16)
__device__ __forceinline__ void gl_lds16(const unsigned short* g, unsigned short* l) {
    __builtin_amdgcn_global_load_lds(
        (const __attribute__((address_space(1))) unsigned int*)g,
        (__attribute__((address_space(3))) unsigned int*)l, 16, 0, 0);
}

// WhFrag[ntile(32)][kk(16)][lane(64)][j(8)] bf16 ; element = Wh[k][n],
// k = kk*16 + (lane>>5)*8 + j, n = ntile*32 + (lane&31)
__global__ void prep_wh(const float* __restrict__ Wh, unsigned short* __restrict__ out) {
    int idx = blockIdx.x * blockDim.x + threadIdx.x; // 0..262143
    int j = idx & 7;
    int lane = (idx >> 3) & 63;
    int kk = (idx >> 9) & 15;
    int ntile = idx >> 13;
    int k = kk * 16 + ((lane >> 5) << 3) + j;
    int n = (ntile << 5) + (lane & 31);
    out[idx] = f2bf(Wh[k * ZDIM + n]);
}

// WxbG[vocab(128)][n(256)][g(4)] bf16 = Wx + b, gate-interleaved: one uint2 = 4 gates
__global__ void prep_wxb4(const float* __restrict__ Wx, const float* __restrict__ b,
                          unsigned short* __restrict__ out) {
    int idx = blockIdx.x * blockDim.x + threadIdx.x; // 0..131071
    int v = idx >> 10;
    int n = (idx >> 2) & 255;
    int g = idx & 3;
    out[idx] = f2bf(Wx[v * ZDIM + g * 256 + n] + b[g * 256 + n]);
}

// WdFrag[ntile(4)][kk(16)][lane(64)][j(8)] bf16 ; element = Wd[k][n]
__global__ void prep_wd(const float* __restrict__ Wd, unsigned short* __restrict__ out) {
    int idx = blockIdx.x * blockDim.x + threadIdx.x; // 0..32767
    int j = idx & 7;
    int lane = (idx >> 3) & 63;
    int kk = (idx >> 9) & 15;
    int nt = idx >> 13;
    int k = kk * 16 + ((lane >> 5) << 3) + j;
    int n = (nt << 5) + (lane & 31);
    out[idx] = f2bf(Wd[k * NUM_CHARS + n]);
}

#define ROWI(i) (((i) & 3) + 8 * ((i) >> 2) + rbase)

__device__ __forceinline__ void gates_store(floatx16 (&acc)[4], floatx16& c_st,
                                            unsigned short* hn, int rbase, int hcol) {
    const float L2E = 1.4426950408889634f;
#pragma unroll
    for (int i = 0; i < 16; ++i) {
        float zi = acc[0][i], zf = acc[1][i], zg = acc[2][i], zo = acc[3][i];
        float si = __builtin_amdgcn_rcpf(1.f + __builtin_amdgcn_exp2f(-zi * L2E));
        float sf = __builtin_amdgcn_rcpf(1.f + __builtin_amdgcn_exp2f(-zf * L2E));
        float so = __builtin_amdgcn_rcpf(1.f + __builtin_amdgcn_exp2f(-zo * L2E));
        float tg = 1.f - 2.f * __builtin_amdgcn_rcpf(1.f + __builtin_amdgcn_exp2f(2.f * L2E * zg));
        float c = sf * c_st[i] + si * tg;
        c_st[i] = c;
        float tc = 1.f - 2.f * __builtin_amdgcn_rcpf(1.f + __builtin_amdgcn_exp2f(2.f * L2E * c));
        hn[ROWI(i) * SH + hcol] = f2bf(so * tc);
    }
}

#define MFMA4(AF, B0, B1, B2, B3)                                                   \
    acc[0] = __builtin_amdgcn_mfma_f32_32x32x16_bf16(AF, B0, acc[0], 0, 0, 0);      \
    acc[1] = __builtin_amdgcn_mfma_f32_32x32x16_bf16(AF, B1, acc[1], 0, 0, 0);      \
    acc[2] = __builtin_amdgcn_mfma_f32_32x32x16_bf16(AF, B2, acc[2], 0, 0, 0);      \
    acc[3] = __builtin_amdgcn_mfma_f32_32x32x16_bf16(AF, B3, acc[3], 0, 0, 0);

// LDS-resident kk (0..2): wlds frag index = ntile*3 + kk
#define L_MFMA(KK) {                                                                 \
    bf16x8 af = *(const bf16x8*)&hb[abase + (KK) * 16];                              \
    bf16x8 b0 = *(const bf16x8*)&wlds[(((0 * 8 + w) * 3 + (KK)) << 9) + (lane << 3)];\
    bf16x8 b1 = *(const bf16x8*)&wlds[(((1 * 8 + w) * 3 + (KK)) << 9) + (lane << 3)];\
    bf16x8 b2 = *(const bf16x8*)&wlds[(((2 * 8 + w) * 3 + (KK)) << 9) + (lane << 3)];\
    bf16x8 b3 = *(const bf16x8*)&wlds[(((3 * 8 + w) * 3 + (KK)) << 9) + (lane << 3)];\
    MFMA4(af, b0, b1, b2, b3)                                                        \
}

// register/AGPR-resident kk (3..8)
#define R_MFMA(KK) {                                                                 \
    bf16x8 af = *(const bf16x8*)&hb[abase + (KK) * 16];                              \
    MFMA4(af, wr[0][(KK) - 3], wr[1][(KK) - 3], wr[2][(KK) - 3], wr[3][(KK) - 3])    \
}

// streamed kk J (9..15): consume slot (J-9)&1, reload it with kk J+2 (within-step only)
#define S_MFMA(J) {                                                                  \
    bf16x8 af = *(const bf16x8*)&hb[abase + (J) * 16];                               \
    MFMA4(af, sw[((J) - 9) & 1][0], sw[((J) - 9) & 1][1],                            \
              sw[((J) - 9) & 1][2], sw[((J) - 9) & 1][3])                            \
    if ((J) + 2 <= 15) {                                                             \
        sw[((J) - 9) & 1][0] = *(const bf16x8*)(wsb[0] + (((J) + 2) << 9));          \
        sw[((J) - 9) & 1][1] = *(const bf16x8*)(wsb[1] + (((J) + 2) << 9));          \
        sw[((J) - 9) & 1][2] = *(const bf16x8*)(wsb[2] + (((J) + 2) << 9));          \
        sw[((J) - 9) & 1][3] = *(const bf16x8*)(wsb[3] + (((J) + 2) << 9));          \
    }                                                                                \
}

// ---- main: 256 blocks x 512 threads; block owns 32 batch rows, 1 block/CU ----
__global__ __launch_bounds__(512) void lstm_main(
    const int* __restrict__ inputs, const unsigned short* __restrict__ WhFrag,
    const unsigned short* __restrict__ WxbG, const unsigned short* __restrict__ WdFrag,
    const float* __restrict__ bd, float* __restrict__ out)
{
    __shared__ unsigned short wlds[32 * 3 * 512];     // 96 KB: kk 0..2 (epilogue: f32 scratch)
    __shared__ unsigned short hbuf[2][32 * SH];       // 33.8 KB double h buffer
    __shared__ int tok[32 * SEQ];                     //  5.0 KB
    __shared__ float red[2][4][32];                   //  1.0 KB

    const int tid = threadIdx.x;
    const int w = tid >> 6;        // wave 0..7; gate g's n-tile = g*8 + w
    const int lane = tid & 63;
    const int r0 = blockIdx.x * 32;

    // stage tokens (coalesced)
    for (int i = tid; i < 32 * SEQ; i += 512) tok[i] = inputs[r0 * SEQ + i];
    // stage Wh kk 0..2 into LDS via DMA: 96 frags; wave w does f = w + 8k, k=0..11
#pragma unroll
    for (int k = 0; k < 12; ++k) {
        int f = w + (k << 3);
        int ntile = f / 3, kkL = f % 3;
        gl_lds16(WhFrag + ((((ntile << 4) + kkL) << 9) + (lane << 3)),
                 &wlds[f << 9]);
    }

    // per-gate streamed-fragment base pointers, lane offset folded in
    const unsigned short* wsb[4];
#pragma unroll
    for (int g = 0; g < 4; ++g)
        wsb[g] = WhFrag + (((g * 8 + w) * 16) << 9) + (lane << 3);

    // resident kk 3..8 (96 regs; overflow parks in AGPRs, read directly by MFMA)
    bf16x8 wr[4][6];
#pragma unroll
    for (int g = 0; g < 4; ++g)
#pragma unroll
        for (int rk = 0; rk < 6; ++rk)
            wr[g][rk] = *(const bf16x8*)(wsb[g] + ((3 + rk) << 9));

    const int hcol = (w << 5) + (lane & 31);
    const int rbase = 4 * (lane >> 5);
    const int abase = (lane & 31) * SH + ((lane >> 5) << 3);

    floatx16 c_st;
#pragma unroll
    for (int i = 0; i < 16; ++i) c_st[i] = 0.f;

    __syncthreads();  // tok + wlds DMA drained

    uint2 xb[16];  // loop-carried gather prefetch

    // ---- t = 0: h0 = 0, z = Wx[token]+b only ----
    {
#pragma unroll
        for (int i = 0; i < 16; ++i)
            xb[i] = *(const uint2*)&WxbG[(tok[ROWI(i) * SEQ] << 10) + (hcol << 2)];
        floatx16 acc[4];
#pragma unroll
        for (int i = 0; i < 16; ++i) {
            uint32_t x = xb[i].x, y = xb[i].y;
            acc[0][i] = __uint_as_float(x << 16);
            acc[1][i] = __uint_as_float(x & 0xFFFF0000u);
            acc[2][i] = __uint_as_float(y << 16);
            acc[3][i] = __uint_as_float(y & 0xFFFF0000u);
        }
        // prefetch for t = 1 (drained by the barrier below)
#pragma unroll
        for (int i = 0; i < 16; ++i)
            xb[i] = *(const uint2*)&WxbG[(tok[ROWI(i) * SEQ + 1] << 10) + (hcol << 2)];
        gates_store(acc, c_st, hbuf[0], rbase, hcol);
    }
    __syncthreads();

    int cur = 0;
    // ---- t = 1..39: read hbuf[cur], write hbuf[cur^1], ONE barrier/step ----
#pragma unroll 1
    for (int t = 1; t < SEQ; ++t) {
        const unsigned short* hb = hbuf[cur];
        unsigned short* hn = hbuf[cur ^ 1];

        // acc init from prefetched gather (zero-wait; xb dies here)
        floatx16 acc[4];
#pragma unroll
        for (int i = 0; i < 16; ++i) {
            uint32_t x = xb[i].x, y = xb[i].y;
            acc[0][i] = __uint_as_float(x << 16);
            acc[1][i] = __uint_as_float(x & 0xFFFF0000u);
            acc[2][i] = __uint_as_float(y << 16);
            acc[3][i] = __uint_as_float(y & 0xFFFF0000u);
        }
        __builtin_amdgcn_sched_barrier(0);  // xb dead before sw window opens

        // preload stream window: kk 9,10 (latency covered by L+R MFMA section)
        bf16x8 sw[2][4];
#pragma unroll
        for (int s = 0; s < 2; ++s) {
            sw[s][0] = *(const bf16x8*)(wsb[0] + ((9 + s) << 9));
            sw[s][1] = *(const bf16x8*)(wsb[1] + ((9 + s) << 9));
            sw[s][2] = *(const bf16x8*)(wsb[2] + ((9 + s) << 9));
            sw[s][3] = *(const bf16x8*)(wsb[3] + ((9 + s) << 9));
        }

        // resident first (covers preload latency), then streamed
        L_MFMA(0) L_MFMA(1) L_MFMA(2)
        R_MFMA(3) R_MFMA(4) R_MFMA(5) R_MFMA(6) R_MFMA(7) R_MFMA(8)
        S_MFMA(9) S_MFMA(10) S_MFMA(11) S_MFMA(12) S_MFMA(13) S_MFMA(14) S_MFMA(15)

        // issue gather for t+1 — in flight through gates; drained by the barrier
        int tn = (t + 1 < SEQ) ? t + 1 : SEQ - 1;
#pragma unroll
        for (int i = 0; i < 16; ++i)
            xb[i] = *(const uint2*)&WxbG[(tok[ROWI(i) * SEQ + tn] << 10) + (hcol << 2)];

        // gates overlap other waves' MFMA tail (no pre-gates barrier)
        gates_store(acc, c_st, hn, rbase, hcol);

        __syncthreads();                 // h_t visible; xb landed
        cur ^= 1;
    }

    // ---- logits = h @ Wd + bd, all 8 waves (K-split), register softmax ----
    float* scratch = (float*)wlds;  // wlds retired; [vt][row32][col32] f32
    const unsigned short* hb = hbuf[cur];  // h_39
    const int vt = w & 3;
    floatx16 accd;
    float p[16];
    float mx[16];
    {
#pragma unroll
        for (int i = 0; i < 16; ++i) accd[i] = 0.f;
        if (w < 4) {
            float bdv = bd[(vt << 5) + (lane & 31)];
#pragma unroll
            for (int i = 0; i < 16; ++i) accd[i] = bdv;
        }
        int kk0 = (w < 4) ? 0 : 8;
#pragma unroll
        for (int kk = 0; kk < 8; ++kk) {
            bf16x8 af = *(const bf16x8*)&hb[abase + (kk0 + kk) * 16];
            bf16x8 bfd = *(const bf16x8*)(WdFrag + ((((vt << 4) + kk0 + kk) << 6) + lane) * 8);
            accd = __builtin_amdgcn_mfma_f32_32x32x16_bf16(af, bfd, accd, 0, 0, 0);
        }
        if (w >= 4) {
#pragma unroll
            for (int i = 0; i < 16; ++i)
                scratch[((vt << 5) + ROWI(i)) * 32 + (lane & 31)] = accd[i];
        }
    }
    __syncthreads();
    if (w < 4) {
#pragma unroll
        for (int i = 0; i < 16; ++i)
            accd[i] += scratch[((vt << 5) + ROWI(i)) * 32 + (lane & 31)];
#pragma unroll
        for (int i = 0; i < 16; ++i) {
            float m = accd[i];
#pragma unroll
            for (int off = 1; off < 32; off <<= 1) m = fmaxf(m, __shfl_xor(m, off, 32));
            mx[i] = m;
        }
        if ((lane & 31) == 0) {
#pragma unroll
            for (int i = 0; i < 16; ++i) red[0][vt][ROWI(i)] = mx[i];
        }
    }
    __syncthreads();
    const float L2E = 1.4426950408889634f;
    if (w < 4) {
#pragma unroll
        for (int i = 0; i < 16; ++i) {
            int r = ROWI(i);
            float M = fmaxf(fmaxf(red[0][0][r], red[0][1][r]),
                            fmaxf(red[0][2][r], red[0][3][r]));
            float e = __builtin_amdgcn_exp2f((accd[i] - M) * L2E);
            p[i] = e;
            float s = e;
#pragma unroll
            for (int off = 1; off < 32; off <<= 1) s += __shfl_xor(s, off, 32);
            mx[i] = s;
        }
        if ((lane & 31) == 0) {
#pragma unroll
            for (int i = 0; i < 16; ++i) red[1][vt][ROWI(i)] = mx[i];
        }
    }
    __syncthreads();
    if (w < 4) {
#pragma unroll
        for (int i = 0; i < 16; ++i) {
            int r = ROWI(i);
            float tot = red[1][0][r] + red[1][1][r] + red[1][2][r] + red[1][3][r];
            out[(size_t)(r0 + r) * NUM_CHARS + (vt << 5) + (lane & 31)] =
                p[i] * __builtin_amdgcn_rcpf(tot);
        }
    }
}

extern "C" void kernel_launch(void* const* d_in, const int* in_sizes, int n_in,
                              void* d_out, int out_size, void* d_ws, size_t ws_size,
                              hipStream_t stream) {
    const int*   inputs = (const int*)d_in[0];
    const float* Wx = (const float*)d_in[1];
    const float* Wh = (const float*)d_in[2];
    const float* b  = (const float*)d_in[3];
    const float* Wd = (const float*)d_in[4];
    const float* bd = (const float*)d_in[5];
    float* out = (float*)d_out;

    unsigned short* WhFrag = (unsigned short*)d_ws;                          // 512 KB
    unsigned short* WxbG   = (unsigned short*)((char*)d_ws + (512 << 10));   // 256 KB
    unsigned short* WdFrag = (unsigned short*)((char*)d_ws + (768 << 10));   //  64 KB

    prep_wh  <<<262144 / 256, 256, 0, stream>>>(Wh, WhFrag);
    prep_wxb4<<<131072 / 256, 256, 0, stream>>>(Wx, b, WxbG);
    prep_wd  <<< 32768 / 256, 256, 0, stream>>>(Wd, WdFrag);
    lstm_main<<<256, 512, 0, stream>>>(inputs, WhFrag, WxbG, WdFrag, bd, out);
}

// Round 20
// 316.521 us; speedup vs baseline: 1.0199x; 1.0199x over previous
//
#include <hip/hip_runtime.h>
#include <stdint.h>

#define NUM_CHARS 128
#define BATCH 8192
#define SEQ 40
#define HIDDEN 256
#define ZDIM 1024   /* 4*HIDDEN */
#define SH 264      /* padded h row stride in ushorts */
/* r18 champion (290us steady) + two overhead cuts:
   (a) three prep kernels fused into one (saves ~2 launch gaps of the ~25us
       harness-vs-dispatch delta);
   (b) tokens stored transposed tokT[t][32]: per-step gather addressing is
       4x int4 LDS reads instead of 16x ds_read_b32 (rows rbase+8q+j map
       exactly to ROWI(i), i=4q+j).
   Core schedule FROZEN at r18: kk 0..3 LDS (128KB DMA-staged), 4..9 wr
   (96 regs, AGPR overflow relief), 10..15 streamed (2-slot within-step ring);
   two barriers/step (r19 proved single-barrier loses); cross-step xb prefetch
   between barrier-1 and gates; 8-wave K-split epilogue. */

typedef __bf16 bf16x8 __attribute__((ext_vector_type(8)));
typedef float floatx16 __attribute__((ext_vector_type(16)));

__device__ __forceinline__ unsigned short f2bf(float f) {
    union { float f; uint32_t u; } v; v.f = f;
    uint32_t u = v.u;
    u += 0x7FFFu + ((u >> 16) & 1u); // RNE
    return (unsigned short)(u >> 16);
}

// 16B-per-lane DMA: global (per-lane addr) -> LDS (wave-uniform base + lane*16)
__device__ __forceinline__ void gl_lds16(const unsigned short* g, unsigned short* l) {
    __builtin_amdgcn_global_load_lds(
        (const __attribute__((address_space(1))) unsigned int*)g,
        (__attribute__((address_space(3))) unsigned int*)l, 16, 0, 0);
}

// Fused prep: [0,262144) WhFrag ; [262144,393216) WxbG ; [393216,425984) WdFrag
// WhFrag[ntile(32)][kk(16)][lane(64)][j(8)] bf16 = Wh[k][n]
// WxbG[vocab(128)][n(256)][g(4)] bf16 = Wx + b (gate-interleaved)
// WdFrag[ntile(4)][kk(16)][lane(64)][j(8)] bf16 = Wd[k][n]
__global__ void prep_all(const float* __restrict__ Wh, const float* __restrict__ Wx,
                         const float* __restrict__ b, const float* __restrict__ Wd,
                         unsigned short* __restrict__ WhFrag,
                         unsigned short* __restrict__ WxbG,
                         unsigned short* __restrict__ WdFrag) {
    int idx = blockIdx.x * blockDim.x + threadIdx.x; // 0..425983
    if (idx < 262144) {
        int j = idx & 7;
        int lane = (idx >> 3) & 63;
        int kk = (idx >> 9) & 15;
        int ntile = idx >> 13;
        int k = kk * 16 + ((lane >> 5) << 3) + j;
        int n = (ntile << 5) + (lane & 31);
        WhFrag[idx] = f2bf(Wh[k * ZDIM + n]);
    } else if (idx < 393216) {
        int i2 = idx - 262144; // 0..131071
        int v = i2 >> 10;
        int n = (i2 >> 2) & 255;
        int g = i2 & 3;
        WxbG[i2] = f2bf(Wx[v * ZDIM + g * 256 + n] + b[g * 256 + n]);
    } else {
        int i3 = idx - 393216; // 0..32767
        int j = i3 & 7;
        int lane = (i3 >> 3) & 63;
        int kk = (i3 >> 9) & 15;
        int nt = i3 >> 13;
        int k = kk * 16 + ((lane >> 5) << 3) + j;
        int n = (nt << 5) + (lane & 31);
        WdFrag[i3] = f2bf(Wd[k * NUM_CHARS + n]);
    }
}

#define ROWI(i) (((i) & 3) + 8 * ((i) >> 2) + rbase)

__device__ __forceinline__ void gates_store(floatx16 (&acc)[4], floatx16& c_st,
                                            unsigned short* hb, int rbase, int hcol) {
    const float L2E = 1.4426950408889634f;
#pragma unroll
    for (int i = 0; i < 16; ++i) {
        float zi = acc[0][i], zf = acc[1][i], zg = acc[2][i], zo = acc[3][i];
        float si = __builtin_amdgcn_rcpf(1.f + __builtin_amdgcn_exp2f(-zi * L2E));
        float sf = __builtin_amdgcn_rcpf(1.f + __builtin_amdgcn_exp2f(-zf * L2E));
        float so = __builtin_amdgcn_rcpf(1.f + __builtin_amdgcn_exp2f(-zo * L2E));
        float tg = 1.f - 2.f * __builtin_amdgcn_rcpf(1.f + __builtin_amdgcn_exp2f(2.f * L2E * zg));
        float c = sf * c_st[i] + si * tg;
        c_st[i] = c;
        float tc = 1.f - 2.f * __builtin_amdgcn_rcpf(1.f + __builtin_amdgcn_exp2f(2.f * L2E * c));
        hb[ROWI(i) * SH + hcol] = f2bf(so * tc);
    }
}

#define MFMA4(AF, B0, B1, B2, B3)                                                   \
    acc[0] = __builtin_amdgcn_mfma_f32_32x32x16_bf16(AF, B0, acc[0], 0, 0, 0);      \
    acc[1] = __builtin_amdgcn_mfma_f32_32x32x16_bf16(AF, B1, acc[1], 0, 0, 0);      \
    acc[2] = __builtin_amdgcn_mfma_f32_32x32x16_bf16(AF, B2, acc[2], 0, 0, 0);      \
    acc[3] = __builtin_amdgcn_mfma_f32_32x32x16_bf16(AF, B3, acc[3], 0, 0, 0);

// LDS-resident kk (0..3): wlds frag index = ntile*4 + kk
#define L_MFMA(KK) {                                                                 \
    bf16x8 af = *(const bf16x8*)&hbuf[abase + (KK) * 16];                            \
    bf16x8 b0 = *(const bf16x8*)&wlds[((((0 * 8 + w) << 2) + (KK)) << 9) + (lane << 3)]; \
    bf16x8 b1 = *(const bf16x8*)&wlds[((((1 * 8 + w) << 2) + (KK)) << 9) + (lane << 3)]; \
    bf16x8 b2 = *(const bf16x8*)&wlds[((((2 * 8 + w) << 2) + (KK)) << 9) + (lane << 3)]; \
    bf16x8 b3 = *(const bf16x8*)&wlds[((((3 * 8 + w) << 2) + (KK)) << 9) + (lane << 3)]; \
    MFMA4(af, b0, b1, b2, b3)                                                        \
}

// register/AGPR-resident kk (4..9)
#define R_MFMA(KK) {                                                                 \
    bf16x8 af = *(const bf16x8*)&hbuf[abase + (KK) * 16];                            \
    MFMA4(af, wr[0][(KK) - 4], wr[1][(KK) - 4], wr[2][(KK) - 4], wr[3][(KK) - 4])    \
}

// streamed kk J (10..15): consume slot (J-10)&1, reload it with kk J+2 (within-step only)
#define S_MFMA(J) {                                                                  \
    bf16x8 af = *(const bf16x8*)&hbuf[abase + (J) * 16];                             \
    MFMA4(af, sw[((J) - 10) & 1][0], sw[((J) - 10) & 1][1],                          \
              sw[((J) - 10) & 1][2], sw[((J) - 10) & 1][3])                          \
    if ((J) + 2 <= 15) {                                                             \
        sw[((J) - 10) & 1][0] = *(const bf16x8*)(wsb[0] + (((J) + 2) << 9));         \
        sw[((J) - 10) & 1][1] = *(const bf16x8*)(wsb[1] + (((J) + 2) << 9));         \
        sw[((J) - 10) & 1][2] = *(const bf16x8*)(wsb[2] + (((J) + 2) << 9));         \
        sw[((J) - 10) & 1][3] = *(const bf16x8*)(wsb[3] + (((J) + 2) << 9));         \
    }                                                                                \
}

// gather xb for step T from transposed token table (4x int4 LDS + 16 uint2 global)
#define GATHER_XB(T) {                                                               \
    _Pragma("unroll")                                                                \
    for (int q = 0; q < 4; ++q) {                                                    \
        int4 tq = *(const int4*)&tokT[(T) * 32 + rbase + (q << 3)];                  \
        xb[(q << 2) + 0] = *(const uint2*)&WxbG[(tq.x << 10) + (hcol << 2)];         \
        xb[(q << 2) + 1] = *(const uint2*)&WxbG[(tq.y << 10) + (hcol << 2)];         \
        xb[(q << 2) + 2] = *(const uint2*)&WxbG[(tq.z << 10) + (hcol << 2)];         \
        xb[(q << 2) + 3] = *(const uint2*)&WxbG[(tq.w << 10) + (hcol << 2)];         \
    }                                                                                \
}

// ---- main: 256 blocks x 512 threads; block owns 32 batch rows, 1 block/CU ----
__global__ __launch_bounds__(512) void lstm_main(
    const int* __restrict__ inputs, const unsigned short* __restrict__ WhFrag,
    const unsigned short* __restrict__ WxbG, const unsigned short* __restrict__ WdFrag,
    const float* __restrict__ bd, float* __restrict__ out)
{
    __shared__ unsigned short wlds[32 * 4 * 512];     // 128 KB: kk 0..3 (epilogue: f32 scratch)
    __shared__ unsigned short hbuf[32 * SH];          // 16.5 KB single h buffer
    __shared__ int tokT[SEQ * 32];                    //  5.0 KB transposed tokens [t][r]
    __shared__ float red[2][4][32];                   //  1.0 KB

    const int tid = threadIdx.x;
    const int w = tid >> 6;        // wave 0..7; gate g's n-tile = g*8 + w
    const int lane = tid & 63;
    const int r0 = blockIdx.x * 32;

    // stage tokens TRANSPOSED: global read coalesced over [r][t], write [t][r]
    for (int i = tid; i < 32 * SEQ; i += 512) {
        int r = i / SEQ, t = i - r * SEQ;
        tokT[t * 32 + r] = inputs[r0 * SEQ + i];
    }
    // stage Wh kk 0..3 into LDS via DMA: frag f = w + 8k (wave-uniform), o = lane
#pragma unroll
    for (int k = 0; k < 16; ++k) {
        int f = w + (k << 3);
        gl_lds16(WhFrag + (((((f >> 2) << 4) + (f & 3)) << 9) + (lane << 3)),
                 &wlds[f << 9]);
    }

    // per-gate streamed-fragment base pointers, lane offset folded in
    const unsigned short* wsb[4];
#pragma unroll
    for (int g = 0; g < 4; ++g)
        wsb[g] = WhFrag + (((g * 8 + w) * 16) << 9) + (lane << 3);

    // resident kk 4..9 (96 regs; overflow parks in AGPRs, read directly by MFMA)
    bf16x8 wr[4][6];
#pragma unroll
    for (int g = 0; g < 4; ++g)
#pragma unroll
        for (int rk = 0; rk < 6; ++rk)
            wr[g][rk] = *(const bf16x8*)(wsb[g] + ((4 + rk) << 9));

    const int hcol = (w << 5) + (lane & 31);
    const int rbase = 4 * (lane >> 5);
    const int abase = (lane & 31) * SH + ((lane >> 5) << 3);

    floatx16 c_st;
#pragma unroll
    for (int i = 0; i < 16; ++i) c_st[i] = 0.f;

    __syncthreads();  // tokT + wlds DMA drained

    uint2 xb[16];  // loop-carried gather prefetch

    // ---- t = 0: h0 = 0, z = Wx[token]+b only ----
    {
        GATHER_XB(0)
        floatx16 acc[4];
#pragma unroll
        for (int i = 0; i < 16; ++i) {
            uint32_t x = xb[i].x, y = xb[i].y;
            acc[0][i] = __uint_as_float(x << 16);
            acc[1][i] = __uint_as_float(x & 0xFFFF0000u);
            acc[2][i] = __uint_as_float(y << 16);
            acc[3][i] = __uint_as_float(y & 0xFFFF0000u);
        }
        // prefetch for t = 1 (drained by the __syncthreads below)
        GATHER_XB(1)
        gates_store(acc, c_st, hbuf, rbase, hcol);
    }
    __syncthreads();

    // ---- t = 1..39 ----
#pragma unroll 1
    for (int t = 1; t < SEQ; ++t) {
        // acc init from prefetched gather (zero-wait; xb dies here)
        floatx16 acc[4];
#pragma unroll
        for (int i = 0; i < 16; ++i) {
            uint32_t x = xb[i].x, y = xb[i].y;
            acc[0][i] = __uint_as_float(x << 16);
            acc[1][i] = __uint_as_float(x & 0xFFFF0000u);
            acc[2][i] = __uint_as_float(y << 16);
            acc[3][i] = __uint_as_float(y & 0xFFFF0000u);
        }
        __builtin_amdgcn_sched_barrier(0);  // xb dead before sw window opens

        // preload stream window: kk 10,11 (latency covered by L+R MFMA section)
        bf16x8 sw[2][4];
#pragma unroll
        for (int s = 0; s < 2; ++s) {
            sw[s][0] = *(const bf16x8*)(wsb[0] + ((10 + s) << 9));
            sw[s][1] = *(const bf16x8*)(wsb[1] + ((10 + s) << 9));
            sw[s][2] = *(const bf16x8*)(wsb[2] + ((10 + s) << 9));
            sw[s][3] = *(const bf16x8*)(wsb[3] + ((10 + s) << 9));
        }

        // resident first (covers preload latency), then streamed
        L_MFMA(0) L_MFMA(1) L_MFMA(2) L_MFMA(3)
        R_MFMA(4) R_MFMA(5) R_MFMA(6) R_MFMA(7) R_MFMA(8) R_MFMA(9)
        S_MFMA(10) S_MFMA(11) S_MFMA(12) S_MFMA(13) S_MFMA(14) S_MFMA(15)

        __syncthreads();                 // barrier-1: all h reads done

        // issue gather for t+1 — sw/af dead; flight covered by gates,
        // drained by barrier-2's vmcnt(0) (keeps lockstep)
        int tn = (t + 1 < SEQ) ? t + 1 : SEQ - 1;
        GATHER_XB(tn)

        gates_store(acc, c_st, hbuf, rbase, hcol);
        __syncthreads();                 // barrier-2: h_t visible, xb landed
    }

    // ---- logits = h @ Wd + bd, all 8 waves (K-split), register softmax ----
    float* scratch = (float*)wlds;  // wlds retired; [vt][row32][col32] f32
    const int vt = w & 3;
    floatx16 accd;
    float p[16];
    float mx[16];
    {
#pragma unroll
        for (int i = 0; i < 16; ++i) accd[i] = 0.f;
        if (w < 4) {
            float bdv = bd[(vt << 5) + (lane & 31)];
#pragma unroll
            for (int i = 0; i < 16; ++i) accd[i] = bdv;
        }
        int kk0 = (w < 4) ? 0 : 8;
#pragma unroll
        for (int kk = 0; kk < 8; ++kk) {
            bf16x8 af = *(const bf16x8*)&hbuf[abase + (kk0 + kk) * 16];
            bf16x8 bfd = *(const bf16x8*)(WdFrag + ((((vt << 4) + kk0 + kk) << 6) + lane) * 8);
            accd = __builtin_amdgcn_mfma_f32_32x32x16_bf16(af, bfd, accd, 0, 0, 0);
        }
        if (w >= 4) {
#pragma unroll
            for (int i = 0; i < 16; ++i)
                scratch[((vt << 5) + ROWI(i)) * 32 + (lane & 31)] = accd[i];
        }
    }
    __syncthreads();
    if (w < 4) {
#pragma unroll
        for (int i = 0; i < 16; ++i)
            accd[i] += scratch[((vt << 5) + ROWI(i)) * 32 + (lane & 31)];
#pragma unroll
        for (int i = 0; i < 16; ++i) {
            float m = accd[i];
#pragma unroll
            for (int off = 1; off < 32; off <<= 1) m = fmaxf(m, __shfl_xor(m, off, 32));
            mx[i] = m;
        }
        if ((lane & 31) == 0) {
#pragma unroll
            for (int i = 0; i < 16; ++i) red[0][vt][ROWI(i)] = mx[i];
        }
    }
    __syncthreads();
    const float L2E = 1.4426950408889634f;
    if (w < 4) {
#pragma unroll
        for (int i = 0; i < 16; ++i) {
            int r = ROWI(i);
            float M = fmaxf(fmaxf(red[0][0][r], red[0][1][r]),
                            fmaxf(red[0][2][r], red[0][3][r]));
            float e = __builtin_amdgcn_exp2f((accd[i] - M) * L2E);
            p[i] = e;
            float s = e;
#pragma unroll
            for (int off = 1; off < 32; off <<= 1) s += __shfl_xor(s, off, 32);
            mx[i] = s;
        }
        if ((lane & 31) == 0) {
#pragma unroll
            for (int i = 0; i < 16; ++i) red[1][vt][ROWI(i)] = mx[i];
        }
    }
    __syncthreads();
    if (w < 4) {
#pragma unroll
        for (int i = 0; i < 16; ++i) {
            int r = ROWI(i);
            float tot = red[1][0][r] + red[1][1][r] + red[1][2][r] + red[1][3][r];
            out[(size_t)(r0 + r) * NUM_CHARS + (vt << 5) + (lane & 31)] =
                p[i] * __builtin_amdgcn_rcpf(tot);
        }
    }
}

extern "C" void kernel_launch(void* const* d_in, const int* in_sizes, int n_in,
                              void* d_out, int out_size, void* d_ws, size_t ws_size,
                              hipStream_t stream) {
    const int*   inputs = (const int*)d_in[0];
    const float* Wx = (const float*)d_in[1];
    const float* Wh = (const float*)d_in[2];
    const float* b  = (const float*)d_in[3];
    const float* Wd = (const float*)d_in[4];
    const float* bd = (const float*)d_in[5];
    float* out = (float*)d_out;

    unsigned short* WhFrag = (unsigned short*)d_ws;                          // 512 KB
    unsigned short* WxbG   = (unsigned short*)((char*)d_ws + (512 << 10));   // 256 KB
    unsigned short* WdFrag = (unsigned short*)((char*)d_ws + (768 << 10));   //  64 KB

    prep_all<<<425984 / 256, 256, 0, stream>>>(Wh, Wx, b, Wd, WhFrag, WxbG, WdFrag);
    lstm_main<<<256, 512, 0, stream>>>(inputs, WhFrag, WxbG, WdFrag, bd, out);
}

// Round 21
// 313.362 us; speedup vs baseline: 1.0302x; 1.0101x over previous
//
#include <hip/hip_runtime.h>
#include <stdint.h>

#define NUM_CHARS 128
#define BATCH 8192
#define SEQ 40
#define HIDDEN 256
#define ZDIM 1024   /* 4*HIDDEN */
#define SH 264      /* padded h row stride in ushorts */
/* FINAL: r18 champion step-loop (290us steady, measured optimum of every lever)
   + fused prep kernel (r20-proven harmless). tokT reverted (r20: +252K bank
   conflicts, +2.4us).
   Structure: 256 blocks x 512 thr, 32 rows/block, 1 block/CU.
   Wh partition: kk 0..3 LDS (128KB, DMA-staged), kk 4..9 resident (96 regs,
   AGPR overflow relief valve — wr5/wr7 bracketed), kk 10..15 streamed
   (2-slot within-step ring). Two barriers/step (lockstep protects L2;
   single-barrier rejected twice). Cross-step xb gather prefetch issued
   between barrier-1 and gates. 8-wave K-split logits epilogue.
   Register law (19 rounds): arch live <= ~116/128 at every point; acc 64 AGPR
   leaves relief; violations -> scratch spill -> L2 thrash (r1/r3/r4/r6/r7/r12). */

typedef __bf16 bf16x8 __attribute__((ext_vector_type(8)));
typedef float floatx16 __attribute__((ext_vector_type(16)));

__device__ __forceinline__ unsigned short f2bf(float f) {
    union { float f; uint32_t u; } v; v.f = f;
    uint32_t u = v.u;
    u += 0x7FFFu + ((u >> 16) & 1u); // RNE
    return (unsigned short)(u >> 16);
}

// 16B-per-lane DMA: global (per-lane addr) -> LDS (wave-uniform base + lane*16)
__device__ __forceinline__ void gl_lds16(const unsigned short* g, unsigned short* l) {
    __builtin_amdgcn_global_load_lds(
        (const __attribute__((address_space(1))) unsigned int*)g,
        (__attribute__((address_space(3))) unsigned int*)l, 16, 0, 0);
}

// Fused prep: [0,262144) WhFrag ; [262144,393216) WxbG ; [393216,425984) WdFrag
__global__ void prep_all(const float* __restrict__ Wh, const float* __restrict__ Wx,
                         const float* __restrict__ b, const float* __restrict__ Wd,
                         unsigned short* __restrict__ WhFrag,
                         unsigned short* __restrict__ WxbG,
                         unsigned short* __restrict__ WdFrag) {
    int idx = blockIdx.x * blockDim.x + threadIdx.x; // 0..425983
    if (idx < 262144) {
        int j = idx & 7;
        int lane = (idx >> 3) & 63;
        int kk = (idx >> 9) & 15;
        int ntile = idx >> 13;
        int k = kk * 16 + ((lane >> 5) << 3) + j;
        int n = (ntile << 5) + (lane & 31);
        WhFrag[idx] = f2bf(Wh[k * ZDIM + n]);
    } else if (idx < 393216) {
        int i2 = idx - 262144; // 0..131071
        int v = i2 >> 10;
        int n = (i2 >> 2) & 255;
        int g = i2 & 3;
        WxbG[i2] = f2bf(Wx[v * ZDIM + g * 256 + n] + b[g * 256 + n]);
    } else {
        int i3 = idx - 393216; // 0..32767
        int j = i3 & 7;
        int lane = (i3 >> 3) & 63;
        int kk = (i3 >> 9) & 15;
        int nt = i3 >> 13;
        int k = kk * 16 + ((lane >> 5) << 3) + j;
        int n = (nt << 5) + (lane & 31);
        WdFrag[i3] = f2bf(Wd[k * NUM_CHARS + n]);
    }
}

#define ROWI(i) (((i) & 3) + 8 * ((i) >> 2) + rbase)

__device__ __forceinline__ void gates_store(floatx16 (&acc)[4], floatx16& c_st,
                                            unsigned short* hb, int rbase, int hcol) {
    const float L2E = 1.4426950408889634f;
#pragma unroll
    for (int i = 0; i < 16; ++i) {
        float zi = acc[0][i], zf = acc[1][i], zg = acc[2][i], zo = acc[3][i];
        float si = __builtin_amdgcn_rcpf(1.f + __builtin_amdgcn_exp2f(-zi * L2E));
        float sf = __builtin_amdgcn_rcpf(1.f + __builtin_amdgcn_exp2f(-zf * L2E));
        float so = __builtin_amdgcn_rcpf(1.f + __builtin_amdgcn_exp2f(-zo * L2E));
        float tg = 1.f - 2.f * __builtin_amdgcn_rcpf(1.f + __builtin_amdgcn_exp2f(2.f * L2E * zg));
        float c = sf * c_st[i] + si * tg;
        c_st[i] = c;
        float tc = 1.f - 2.f * __builtin_amdgcn_rcpf(1.f + __builtin_amdgcn_exp2f(2.f * L2E * c));
        hb[ROWI(i) * SH + hcol] = f2bf(so * tc);
    }
}

#define MFMA4(AF, B0, B1, B2, B3)                                                   \
    acc[0] = __builtin_amdgcn_mfma_f32_32x32x16_bf16(AF, B0, acc[0], 0, 0, 0);      \
    acc[1] = __builtin_amdgcn_mfma_f32_32x32x16_bf16(AF, B1, acc[1], 0, 0, 0);      \
    acc[2] = __builtin_amdgcn_mfma_f32_32x32x16_bf16(AF, B2, acc[2], 0, 0, 0);      \
    acc[3] = __builtin_amdgcn_mfma_f32_32x32x16_bf16(AF, B3, acc[3], 0, 0, 0);

// LDS-resident kk (0..3): wlds frag index = ntile*4 + kk
#define L_MFMA(KK) {                                                                 \
    bf16x8 af = *(const bf16x8*)&hbuf[abase + (KK) * 16];                            \
    bf16x8 b0 = *(const bf16x8*)&wlds[((((0 * 8 + w) << 2) + (KK)) << 9) + (lane << 3)]; \
    bf16x8 b1 = *(const bf16x8*)&wlds[((((1 * 8 + w) << 2) + (KK)) << 9) + (lane << 3)]; \
    bf16x8 b2 = *(const bf16x8*)&wlds[((((2 * 8 + w) << 2) + (KK)) << 9) + (lane << 3)]; \
    bf16x8 b3 = *(const bf16x8*)&wlds[((((3 * 8 + w) << 2) + (KK)) << 9) + (lane << 3)]; \
    MFMA4(af, b0, b1, b2, b3)                                                        \
}

// register/AGPR-resident kk (4..9)
#define R_MFMA(KK) {                                                                 \
    bf16x8 af = *(const bf16x8*)&hbuf[abase + (KK) * 16];                            \
    MFMA4(af, wr[0][(KK) - 4], wr[1][(KK) - 4], wr[2][(KK) - 4], wr[3][(KK) - 4])    \
}

// streamed kk J (10..15): consume slot (J-10)&1, reload it with kk J+2 (within-step only)
#define S_MFMA(J) {                                                                  \
    bf16x8 af = *(const bf16x8*)&hbuf[abase + (J) * 16];                             \
    MFMA4(af, sw[((J) - 10) & 1][0], sw[((J) - 10) & 1][1],                          \
              sw[((J) - 10) & 1][2], sw[((J) - 10) & 1][3])                          \
    if ((J) + 2 <= 15) {                                                             \
        sw[((J) - 10) & 1][0] = *(const bf16x8*)(wsb[0] + (((J) + 2) << 9));         \
        sw[((J) - 10) & 1][1] = *(const bf16x8*)(wsb[1] + (((J) + 2) << 9));         \
        sw[((J) - 10) & 1][2] = *(const bf16x8*)(wsb[2] + (((J) + 2) << 9));         \
        sw[((J) - 10) & 1][3] = *(const bf16x8*)(wsb[3] + (((J) + 2) << 9));         \
    }                                                                                \
}

// ---- main: 256 blocks x 512 threads; block owns 32 batch rows, 1 block/CU ----
__global__ __launch_bounds__(512) void lstm_main(
    const int* __restrict__ inputs, const unsigned short* __restrict__ WhFrag,
    const unsigned short* __restrict__ WxbG, const unsigned short* __restrict__ WdFrag,
    const float* __restrict__ bd, float* __restrict__ out)
{
    __shared__ unsigned short wlds[32 * 4 * 512];     // 128 KB: kk 0..3 (epilogue: f32 scratch)
    __shared__ unsigned short hbuf[32 * SH];          // 16.5 KB single h buffer
    __shared__ int tok[32 * SEQ];                     //  5.0 KB
    __shared__ float red[2][4][32];                   //  1.0 KB

    const int tid = threadIdx.x;
    const int w = tid >> 6;        // wave 0..7; gate g's n-tile = g*8 + w
    const int lane = tid & 63;
    const int r0 = blockIdx.x * 32;

    // stage tokens (coalesced, row-major — conflict-free broadcast reads in-loop)
    for (int i = tid; i < 32 * SEQ; i += 512) tok[i] = inputs[r0 * SEQ + i];
    // stage Wh kk 0..3 into LDS via DMA: frag f = w + 8k (wave-uniform), o = lane
#pragma unroll
    for (int k = 0; k < 16; ++k) {
        int f = w + (k << 3);
        gl_lds16(WhFrag + (((((f >> 2) << 4) + (f & 3)) << 9) + (lane << 3)),
                 &wlds[f << 9]);
    }

    // per-gate streamed-fragment base pointers, lane offset folded in
    const unsigned short* wsb[4];
#pragma unroll
    for (int g = 0; g < 4; ++g)
        wsb[g] = WhFrag + (((g * 8 + w) * 16) << 9) + (lane << 3);

    // resident kk 4..9 (96 regs; overflow parks in AGPRs, read directly by MFMA)
    bf16x8 wr[4][6];
#pragma unroll
    for (int g = 0; g < 4; ++g)
#pragma unroll
        for (int rk = 0; rk < 6; ++rk)
            wr[g][rk] = *(const bf16x8*)(wsb[g] + ((4 + rk) << 9));

    const int hcol = (w << 5) + (lane & 31);
    const int rbase = 4 * (lane >> 5);
    const int abase = (lane & 31) * SH + ((lane >> 5) << 3);

    floatx16 c_st;
#pragma unroll
    for (int i = 0; i < 16; ++i) c_st[i] = 0.f;

    __syncthreads();  // tok + wlds DMA drained

    uint2 xb[16];  // loop-carried gather prefetch

    // ---- t = 0: h0 = 0, z = Wx[token]+b only ----
    {
#pragma unroll
        for (int i = 0; i < 16; ++i)
            xb[i] = *(const uint2*)&WxbG[(tok[ROWI(i) * SEQ] << 10) + (hcol << 2)];
        floatx16 acc[4];
#pragma unroll
        for (int i = 0; i < 16; ++i) {
            uint32_t x = xb[i].x, y = xb[i].y;
            acc[0][i] = __uint_as_float(x << 16);
            acc[1][i] = __uint_as_float(x & 0xFFFF0000u);
            acc[2][i] = __uint_as_float(y << 16);
            acc[3][i] = __uint_as_float(y & 0xFFFF0000u);
        }
        // prefetch for t = 1
#pragma unroll
        for (int i = 0; i < 16; ++i)
            xb[i] = *(const uint2*)&WxbG[(tok[ROWI(i) * SEQ + 1] << 10) + (hcol << 2)];
        gates_store(acc, c_st, hbuf, rbase, hcol);
    }
    __syncthreads();

    // ---- t = 1..39 ----
#pragma unroll 1
    for (int t = 1; t < SEQ; ++t) {
        // acc init from prefetched gather (zero-wait; xb dies here)
        floatx16 acc[4];
#pragma unroll
        for (int i = 0; i < 16; ++i) {
            uint32_t x = xb[i].x, y = xb[i].y;
            acc[0][i] = __uint_as_float(x << 16);
            acc[1][i] = __uint_as_float(x & 0xFFFF0000u);
            acc[2][i] = __uint_as_float(y << 16);
            acc[3][i] = __uint_as_float(y & 0xFFFF0000u);
        }
        __builtin_amdgcn_sched_barrier(0);  // xb dead before sw window opens

        // preload stream window: kk 10,11 (latency covered by L+R MFMA section)
        bf16x8 sw[2][4];
#pragma unroll
        for (int s = 0; s < 2; ++s) {
            sw[s][0] = *(const bf16x8*)(wsb[0] + ((10 + s) << 9));
            sw[s][1] = *(const bf16x8*)(wsb[1] + ((10 + s) << 9));
            sw[s][2] = *(const bf16x8*)(wsb[2] + ((10 + s) << 9));
            sw[s][3] = *(const bf16x8*)(wsb[3] + ((10 + s) << 9));
        }

        // resident first (covers preload latency), then streamed
        L_MFMA(0) L_MFMA(1) L_MFMA(2) L_MFMA(3)
        R_MFMA(4) R_MFMA(5) R_MFMA(6) R_MFMA(7) R_MFMA(8) R_MFMA(9)
        S_MFMA(10) S_MFMA(11) S_MFMA(12) S_MFMA(13) S_MFMA(14) S_MFMA(15)

        __syncthreads();                 // barrier-1: all h reads done

        // issue gather for t+1 — sw/af dead; flight covered by gates,
        // drained by barrier-2's vmcnt(0) (keeps lockstep)
        int tn = (t + 1 < SEQ) ? t + 1 : SEQ - 1;
#pragma unroll
        for (int i = 0; i < 16; ++i)
            xb[i] = *(const uint2*)&WxbG[(tok[ROWI(i) * SEQ + tn] << 10) + (hcol << 2)];

        gates_store(acc, c_st, hbuf, rbase, hcol);
        __syncthreads();                 // barrier-2: h_t visible, xb landed
    }

    // ---- logits = h @ Wd + bd, all 8 waves (K-split), register softmax ----
    float* scratch = (float*)wlds;  // wlds retired; [vt][row32][col32] f32
    const int vt = w & 3;
    floatx16 accd;
    float p[16];
    float mx[16];
    {
#pragma unroll
        for (int i = 0; i < 16; ++i) accd[i] = 0.f;
        if (w < 4) {
            float bdv = bd[(vt << 5) + (lane & 31)];
#pragma unroll
            for (int i = 0; i < 16; ++i) accd[i] = bdv;
        }
        int kk0 = (w < 4) ? 0 : 8;
#pragma unroll
        for (int kk = 0; kk < 8; ++kk) {
            bf16x8 af = *(const bf16x8*)&hbuf[abase + (kk0 + kk) * 16];
            bf16x8 bfd = *(const bf16x8*)(WdFrag + ((((vt << 4) + kk0 + kk) << 6) + lane) * 8);
            accd = __builtin_amdgcn_mfma_f32_32x32x16_bf16(af, bfd, accd, 0, 0, 0);
        }
        if (w >= 4) {
#pragma unroll
            for (int i = 0; i < 16; ++i)
                scratch[((vt << 5) + ROWI(i)) * 32 + (lane & 31)] = accd[i];
        }
    }
    __syncthreads();
    if (w < 4) {
#pragma unroll
        for (int i = 0; i < 16; ++i)
            accd[i] += scratch[((vt << 5) + ROWI(i)) * 32 + (lane & 31)];
#pragma unroll
        for (int i = 0; i < 16; ++i) {
            float m = accd[i];
#pragma unroll
            for (int off = 1; off < 32; off <<= 1) m = fmaxf(m, __shfl_xor(m, off, 32));
            mx[i] = m;
        }
        if ((lane & 31) == 0) {
#pragma unroll
            for (int i = 0; i < 16; ++i) red[0][vt][ROWI(i)] = mx[i];
        }
    }
    __syncthreads();
    const float L2E = 1.4426950408889634f;
    if (w < 4) {
#pragma unroll
        for (int i = 0; i < 16; ++i) {
            int r = ROWI(i);
            float M = fmaxf(fmaxf(red[0][0][r], red[0][1][r]),
                            fmaxf(red[0][2][r], red[0][3][r]));
            float e = __builtin_amdgcn_exp2f((accd[i] - M) * L2E);
            p[i] = e;
            float s = e;
#pragma unroll
            for (int off = 1; off < 32; off <<= 1) s += __shfl_xor(s, off, 32);
            mx[i] = s;
        }
        if ((lane & 31) == 0) {
#pragma unroll
            for (int i = 0; i < 16; ++i) red[1][vt][ROWI(i)] = mx[i];
        }
    }
    __syncthreads();
    if (w < 4) {
#pragma unroll
        for (int i = 0; i < 16; ++i) {
            int r = ROWI(i);
            float tot = red[1][0][r] + red[1][1][r] + red[1][2][r] + red[1][3][r];
            out[(size_t)(r0 + r) * NUM_CHARS + (vt << 5) + (lane & 31)] =
                p[i] * __builtin_amdgcn_rcpf(tot);
        }
    }
}

extern "C" void kernel_launch(void* const* d_in, const int* in_sizes, int n_in,
                              void* d_out, int out_size, void* d_ws, size_t ws_size,
                              hipStream_t stream) {
    const int*   inputs = (const int*)d_in[0];
    const float* Wx = (const float*)d_in[1];
    const float* Wh = (const float*)d_in[2];
    const float* b  = (const float*)d_in[3];
    const float* Wd = (const float*)d_in[4];
    const float* bd = (const float*)d_in[5];
    float* out = (float*)d_out;

    unsigned short* WhFrag = (unsigned short*)d_ws;                          // 512 KB
    unsigned short* WxbG   = (unsigned short*)((char*)d_ws + (512 << 10));   // 256 KB
    unsigned short* WdFrag = (unsigned short*)((char*)d_ws + (768 << 10));   //  64 KB

    prep_all<<<425984 / 256, 256, 0, stream>>>(Wh, Wx, b, Wd, WhFrag, WxbG, WdFrag);
    lstm_main<<<256, 512, 0, stream>>>(inputs, WhFrag, WxbG, WdFrag, bd, out);
}